// Round 13
// baseline (38121.414 us; speedup 1.0000x reference)
//
#include <hip/hip_runtime.h>
#include <stdint.h>

// GRU encoder: VOCAB=50257, EMBED=HIDDEN=1024, SEQ=4096.
// Phase 1: x-projections, output transposed [row][t].
// Phase 2: 4096-step scan, 64 WGs x 512 threads, fused (tag|value) u64 cells,
//          RMW publish. ROUND-13: R12's single-asm-block 4-slot pipelined
//          poll with the constraint bug fixed (want/budget are VGPR "v"
//          operands; R12's "s" constraints forced an illegal VGPR->SGPR
//          copy). Slots in clobbered v48-v63: no compiler-visible register
//          ever holds an un-landed load (R11's failure class designed out).
//          Samples the cell every ~RT/4 instead of every RT.

#define HID    1024
#define SEQLEN 4096
#define NWG    64
#define RPW    16      // hidden rows per WG
#define BLOCK  512     // 8 waves; wave w owns rows 16g+2w, 16g+2w+1

typedef unsigned long long u64;

// ---------------------------------------------------------------------------
// Phase 1: CT[i][t] = sum_e emb[seq[t],e] * W[i,e]   (transposed output)
// ---------------------------------------------------------------------------
__global__ __launch_bounds__(256) void proj_gemm(
    const int* __restrict__ seq, const float* __restrict__ emb,
    const float* __restrict__ Wrx, const float* __restrict__ Wzx,
    const float* __restrict__ Wx,
    float* __restrict__ xrT, float* __restrict__ xzT, float* __restrict__ xhT)
{
  __shared__ float As[32][68];   // [k][t]
  __shared__ float Bs[32][68];   // [k][i]
  __shared__ int   idx[64];

  const float* W = (blockIdx.z == 0) ? Wrx : (blockIdx.z == 1) ? Wzx : Wx;
  float*       C = (blockIdx.z == 0) ? xrT : (blockIdx.z == 1) ? xzT : xhT;

  const int tid = threadIdx.x;
  const int t0 = blockIdx.y * 64;
  const int i0 = blockIdx.x * 64;
  if (tid < 64) idx[tid] = seq[t0 + tid];
  __syncthreads();

  float acc[4][4] = {};                     // acc[i][j]: i-dim x t-dim
  const int tx = tid & 15, ty = tid >> 4;
  const int c4 = (tid & 7) * 4;
  const int r8 = tid >> 3;

  for (int k0 = 0; k0 < HID; k0 += 32) {
    for (int l = 0; l < 2; ++l) {
      const int rr = r8 + l * 32;
      float4 av = *(const float4*)(emb + (size_t)idx[rr] * HID + k0 + c4);
      As[c4+0][rr]=av.x; As[c4+1][rr]=av.y; As[c4+2][rr]=av.z; As[c4+3][rr]=av.w;
      float4 bv = *(const float4*)(W + (size_t)(i0 + rr) * HID + k0 + c4);
      Bs[c4+0][rr]=bv.x; Bs[c4+1][rr]=bv.y; Bs[c4+2][rr]=bv.z; Bs[c4+3][rr]=bv.w;
    }
    __syncthreads();
    #pragma unroll
    for (int k = 0; k < 32; ++k) {
      float a[4], b[4];
      *(float4*)a = *(const float4*)&Bs[k][ty * 4];   // i-dim (rows of CT)
      *(float4*)b = *(const float4*)&As[k][tx * 4];   // t-dim (cols of CT)
      #pragma unroll
      for (int i = 0; i < 4; ++i)
        #pragma unroll
        for (int j = 0; j < 4; ++j)
          acc[i][j] = fmaf(a[i], b[j], acc[i][j]);
    }
    __syncthreads();
  }
  #pragma unroll
  for (int i = 0; i < 4; ++i) {
    float4 v = make_float4(acc[i][0], acc[i][1], acc[i][2], acc[i][3]);
    *(float4*)(C + (size_t)(i0 + ty * 4 + i) * SEQLEN + t0 + tx * 4) = v;
  }
}

// ---------------------------------------------------------------------------
// Fused-cell primitives. Cell = u64 {low: f32 bits, high: step tag}.
// PUBLISH: agent-scope atomic exchange (RMW executes at the MALL).
// ---------------------------------------------------------------------------
__device__ __forceinline__ void publish2(u64* cells, int row, float a, float b,
                                         unsigned tag) {
  u64 ca = ((u64)tag << 32) | (u64)__float_as_uint(a);
  u64 cb = ((u64)tag << 32) | (u64)__float_as_uint(b);
  (void)__hip_atomic_exchange(&cells[row],     ca, __ATOMIC_RELAXED,
                              __HIP_MEMORY_SCOPE_AGENT);
  (void)__hip_atomic_exchange(&cells[row + 1], cb, __ATOMIC_RELAXED,
                              __HIP_MEMORY_SCOPE_AGENT);
}

// 4-slot pipelined poll of one 16B cell pair, entirely inside one asm block.
// Slots live in v[48:63] (clobbered): slot k = v[48+4k..51+4k], tags at
// +1/+3, values at +0/+2. vmcnt(3) lands the checked (oldest) slot --
// in-order vmcnt; foreign in-flight VMEM only makes the wait stricter.
// Wave-collective exit when all active lanes' checked slot has both tags ==
// want (exec-AND via s_andn2). Matched values leave slot regs BEFORE the
// final vmcnt(0) drain (late re-issues may overwrite slot regs at drain).
// Budget in a VGPR bails to garbage exit (absmax fail, not a hang).
__device__ __forceinline__ float2 poll_pair(const u64* cells, int pair,
                                            unsigned want, int* budget) {
  const u64* p = cells + 2 * pair;
  float r0, r1;
  int bud = *budget;
  asm volatile(
    "global_load_dwordx4 v[48:51], %[p], off sc0 sc1\n\t"
    "global_load_dwordx4 v[52:55], %[p], off sc0 sc1\n\t"
    "global_load_dwordx4 v[56:59], %[p], off sc0 sc1\n\t"
    "global_load_dwordx4 v[60:63], %[p], off sc0 sc1\n"
    "1:\n\t"
    "s_waitcnt vmcnt(3)\n\t"
    "v_cmp_eq_u32 vcc, %[want], v49\n\t"
    "v_cmp_eq_u32 s[90:91], %[want], v51\n\t"
    "s_and_b64 s[90:91], vcc, s[90:91]\n\t"
    "s_andn2_b64 s[92:93], exec, s[90:91]\n\t"
    "s_cbranch_scc0 5f\n\t"
    "global_load_dwordx4 v[48:51], %[p], off sc0 sc1\n\t"
    "s_waitcnt vmcnt(3)\n\t"
    "v_cmp_eq_u32 vcc, %[want], v53\n\t"
    "v_cmp_eq_u32 s[90:91], %[want], v55\n\t"
    "s_and_b64 s[90:91], vcc, s[90:91]\n\t"
    "s_andn2_b64 s[92:93], exec, s[90:91]\n\t"
    "s_cbranch_scc0 6f\n\t"
    "global_load_dwordx4 v[52:55], %[p], off sc0 sc1\n\t"
    "s_waitcnt vmcnt(3)\n\t"
    "v_cmp_eq_u32 vcc, %[want], v57\n\t"
    "v_cmp_eq_u32 s[90:91], %[want], v59\n\t"
    "s_and_b64 s[90:91], vcc, s[90:91]\n\t"
    "s_andn2_b64 s[92:93], exec, s[90:91]\n\t"
    "s_cbranch_scc0 7f\n\t"
    "global_load_dwordx4 v[56:59], %[p], off sc0 sc1\n\t"
    "s_waitcnt vmcnt(3)\n\t"
    "v_cmp_eq_u32 vcc, %[want], v61\n\t"
    "v_cmp_eq_u32 s[90:91], %[want], v63\n\t"
    "s_and_b64 s[90:91], vcc, s[90:91]\n\t"
    "s_andn2_b64 s[92:93], exec, s[90:91]\n\t"
    "s_cbranch_scc0 8f\n\t"
    "global_load_dwordx4 v[60:63], %[p], off sc0 sc1\n\t"
    "v_subrev_u32 %[bud], 1, %[bud]\n\t"
    "v_cmp_lt_i32 vcc, 0, %[bud]\n\t"
    "s_cbranch_vccnz 1b\n"
    "5:\n\t"
    "v_mov_b32 %[r0], v48\n\t"
    "v_mov_b32 %[r1], v50\n\t"
    "s_branch 9f\n"
    "6:\n\t"
    "v_mov_b32 %[r0], v52\n\t"
    "v_mov_b32 %[r1], v54\n\t"
    "s_branch 9f\n"
    "7:\n\t"
    "v_mov_b32 %[r0], v56\n\t"
    "v_mov_b32 %[r1], v58\n\t"
    "s_branch 9f\n"
    "8:\n\t"
    "v_mov_b32 %[r0], v60\n\t"
    "v_mov_b32 %[r1], v62\n"
    "9:\n\t"
    "s_waitcnt vmcnt(0)"
    : [r0] "=&v"(r0), [r1] "=&v"(r1), [bud] "+v"(bud)
    : [p] "v"(p), [want] "v"(want)
    : "vcc", "s90", "s91", "s92", "s93",
      "v48","v49","v50","v51","v52","v53","v54","v55",
      "v56","v57","v58","v59","v60","v61","v62","v63",
      "memory");
  *budget = bud;
  return make_float2(r0, r1);
}

// ---------------------------------------------------------------------------
// Phase 2: persistent scan. WG g owns rows [16g,16g+16); wave w (of 8) owns
// rows 16g+2w,+1; lane l covers h-columns {q*256+4l+j} (q-strided,
// conflict-free LDS). Consumer thread tid polls cells {2tid, 2tid+1}.
// Per step: poll h -> B1 -> gates -> publish r*h -> poll rh -> B2 ->
// candidate -> publish h. 2 visibility events, 2 barriers per step.
// ---------------------------------------------------------------------------
__global__ __launch_bounds__(BLOCK, 2) void rnn_scan(
    const float* __restrict__ Wzh, const float* __restrict__ Wrh,
    const float* __restrict__ Whh,
    const float* __restrict__ xzT, const float* __restrict__ xrT,
    const float* __restrict__ xhT,
    u64* __restrict__ hcell,     // [2][HID]
    u64* __restrict__ rhcell,    // [2][HID]
    float* __restrict__ out)
{
  const int tid  = threadIdx.x;
  const int wave = tid >> 6, lane = tid & 63;
  const int g    = blockIdx.x;
  const int rowA = g * RPW + wave * 2;

  __shared__ float h_lds[HID];
  __shared__ float rh_lds[HID];

  // Weights: wgt[m][rr][q*4+j] = Wm[rowA+rr][q*256 + 4*lane + j].
  float wgt[3][2][16];
  #pragma unroll
  for (int m = 0; m < 3; ++m) {
    const float* Wm = (m == 0) ? Wzh : (m == 1) ? Wrh : Whh;
    #pragma unroll
    for (int rr = 0; rr < 2; ++rr) {
      const float* p = Wm + (size_t)(rowA + rr) * HID + lane * 4;
      #pragma unroll
      for (int q = 0; q < 4; ++q) {
        float4 v = *(const float4*)(p + q * 256);
        wgt[m][rr][q*4+0] = v.x; wgt[m][rr][q*4+1] = v.y;
        wgt[m][rr][q*4+2] = v.z; wgt[m][rr][q*4+3] = v.w;
      }
    }
  }

  int budget = 1 << 21;
  float xzv[2], xrv[2], xhv[2], zv[2], hprev[2];

  for (int t = 1; t <= SEQLEN; ++t) {
    // ---- exchange 1: h_{t-1} (tag t-1, parity (t-1)&1) ----
    if (t == 1) {
      *(float2*)&h_lds[2 * tid] = make_float2(0.f, 0.f);
    } else {
      float2 hv = poll_pair(hcell + ((t - 1) & 1) * HID, tid,
                            (unsigned)(t - 1), &budget);
      *(float2*)&h_lds[2 * tid] = hv;
    }

    // x rows ([row][t] layout -> L1-hot): hides under B1.
    if (lane == 0) {
      #pragma unroll
      for (int rr = 0; rr < 2; ++rr) {
        xzv[rr] = xzT[(size_t)(rowA + rr) * SEQLEN + (t - 1)];
        xrv[rr] = xrT[(size_t)(rowA + rr) * SEQLEN + (t - 1)];
        xhv[rr] = xhT[(size_t)(rowA + rr) * SEQLEN + (t - 1)];
      }
    }
    __syncthreads();                                   // [B1]

    // gate dots over q-strided 16 columns, 64-lane shuffle reduce.
    float hr[16];
    #pragma unroll
    for (int q = 0; q < 4; ++q)
      *(float4*)&hr[q*4] = *(const float4*)&h_lds[q * 256 + lane * 4];
    float az[2] = {0.f, 0.f}, ar[2] = {0.f, 0.f};
    #pragma unroll
    for (int rr = 0; rr < 2; ++rr)
      #pragma unroll
      for (int c = 0; c < 16; ++c) {
        az[rr] = fmaf(wgt[0][rr][c], hr[c], az[rr]);
        ar[rr] = fmaf(wgt[1][rr][c], hr[c], ar[rr]);
      }
    #pragma unroll
    for (int m = 1; m < 64; m <<= 1) {
      az[0] += __shfl_xor(az[0], m, 64);
      az[1] += __shfl_xor(az[1], m, 64);
      ar[0] += __shfl_xor(ar[0], m, 64);
      ar[1] += __shfl_xor(ar[1], m, 64);
    }
    if (lane == 0) {
      float rh[2];
      #pragma unroll
      for (int rr = 0; rr < 2; ++rr) {
        hprev[rr] = h_lds[rowA + rr];
        zv[rr]    = 1.f / (1.f + __expf(-(xzv[rr] + az[rr])));
        float rg  = 1.f / (1.f + __expf(-(xrv[rr] + ar[rr])));
        rh[rr]    = rg * hprev[rr];
      }
      publish2(rhcell + (t & 1) * HID, rowA, rh[0], rh[1], (unsigned)t);
    }

    // ---- exchange 2: (r*h)_t (tag t, parity t&1) ----
    {
      float2 rv = poll_pair(rhcell + (t & 1) * HID, tid, (unsigned)t, &budget);
      *(float2*)&rh_lds[2 * tid] = rv;
    }
    __syncthreads();                                   // [B2]

    float rr16[16];
    #pragma unroll
    for (int q = 0; q < 4; ++q)
      *(float4*)&rr16[q*4] = *(const float4*)&rh_lds[q * 256 + lane * 4];
    float ac[2] = {0.f, 0.f};
    #pragma unroll
    for (int rr = 0; rr < 2; ++rr)
      #pragma unroll
      for (int c = 0; c < 16; ++c)
        ac[rr] = fmaf(wgt[2][rr][c], rr16[c], ac[rr]);
    #pragma unroll
    for (int m = 1; m < 64; m <<= 1) {
      ac[0] += __shfl_xor(ac[0], m, 64);
      ac[1] += __shfl_xor(ac[1], m, 64);
    }
    if (lane == 0) {
      float hn[2];
      #pragma unroll
      for (int rr = 0; rr < 2; ++rr) {
        float cand = tanhf(xhv[rr] + ac[rr]);
        hn[rr]     = zv[rr] * hprev[rr] + (1.f - zv[rr]) * cand;
      }
      publish2(hcell + (t & 1) * HID, rowA, hn[0], hn[1], (unsigned)t);
      if (t == SEQLEN) { out[rowA] = hn[0]; out[rowA + 1] = hn[1]; }
    }
  }
}

// ---------------------------------------------------------------------------
extern "C" void kernel_launch(void* const* d_in, const int* in_sizes, int n_in,
                              void* d_out, int out_size, void* d_ws, size_t ws_size,
                              hipStream_t stream) {
  (void)in_sizes; (void)n_in; (void)out_size; (void)ws_size;

  const int*   seq = (const int*)d_in[0];
  const float* emb = (const float*)d_in[1];
  const float* Wrx = (const float*)d_in[2];
  const float* Wrh = (const float*)d_in[3];
  const float* Wzx = (const float*)d_in[4];
  const float* Wzh = (const float*)d_in[5];
  const float* Wx  = (const float*)d_in[6];
  const float* Wh  = (const float*)d_in[7];

  char* ws = (char*)d_ws;
  const size_t PROJ = (size_t)SEQLEN * HID * sizeof(float);   // 16 MB each
  float* xrT    = (float*)(ws);
  float* xzT    = (float*)(ws + PROJ);
  float* xhT    = (float*)(ws + 2 * PROJ);
  u64*   hcell  = (u64*)(ws + 3 * PROJ);                      // [2][HID]
  u64*   rhcell = hcell + 2 * HID;                            // [2][HID]

  // Tag reset every launch: 0xFFFFFFFF never matches a wanted tag in [1,4096].
  (void)hipMemsetAsync(hcell, 0xFF, 4 * HID * sizeof(u64), stream);

  proj_gemm<<<dim3(HID / 64, SEQLEN / 64, 3), 256, 0, stream>>>(
      seq, emb, Wrx, Wzx, Wx, xrT, xzT, xhT);

  rnn_scan<<<dim3(NWG), BLOCK, 0, stream>>>(
      Wzh, Wrh, Wh, xzT, xrT, xhT, hcell, rhcell, (float*)d_out);
}